// Round 6
// baseline (879.819 us; speedup 1.0000x reference)
//
#include <hip/hip_runtime.h>
#include <hip/hip_bf16.h>
#include <math.h>

// RGA module: B=64, C=128, HW=784, IC=32, IS=196, DS=49, DC=8.
// Rank-32 factorization removes Gs [b,784,784] and Gc [b,128,128] entirely.
// Runtime dtype detection (bf16 vs f32 inputs) via exponent-sanity probe.
// R5: k8 channel projections on MFMA bf16. R6: k4 o-loop split across 4 waves.

#define BB 64
#define CC 128
#define HW 784
#define IC 32
#define IS 196
#define DS 49

// ---- wf (converted f32 inputs) offsets, padded to 4-float alignment ----
#define O_THW 0
#define O_PHW 4096
#define O_GGSW 8192
#define O_GXSW 315520
#define O_WS1W 319616
#define O_WS2W 329272
#define O_THCW 329324
#define O_PHCW 482988
#define O_GGCW 636652
#define O_GXCW 644844
#define O_WC1W 798508
#define O_WC2W 798772
#define O_THS 798780
#define O_THB 798812
#define O_PHS 798844
#define O_PHB 798876
#define O_GGSS 798908
#define O_GGSB 799104
#define O_GXSS 799300
#define O_GXSB 799332
#define O_WS1S 799364
#define O_WS1B 799416
#define O_WS2S 799468
#define O_WS2B 799472
#define O_THCS 799476
#define O_THCB 799672
#define O_PHCS 799868
#define O_PHCB 800064
#define O_GGCS 800260
#define O_GGCB 800292
#define O_GXCS 800324
#define O_GXCB 800520
#define O_WC1S 800716
#define O_WC1B 800724
#define O_WC2S 800732
#define O_WC2B 800736
#define WF_TOTAL 800768

static const int SRC_SIZES[36] = {
  4096,4096,307328,4096,9653,49,153664,153664,8192,153664,264,8,
  32,32,32,32,196,196,32,32,49,49,1,1,196,196,196,196,32,32,196,196,8,8,1,1};
static const int DST_OFF[36] = {
  O_THW,O_PHW,O_GGSW,O_GXSW,O_WS1W,O_WS2W,O_THCW,O_PHCW,O_GGCW,O_GXCW,O_WC1W,O_WC2W,
  O_THS,O_THB,O_PHS,O_PHB,O_GGSS,O_GGSB,O_GXSS,O_GXSB,O_WS1S,O_WS1B,O_WS2S,O_WS2B,
  O_THCS,O_THCB,O_PHCS,O_PHCB,O_GGCS,O_GGCB,O_GXCS,O_GXCB,O_WC1S,O_WC1B,O_WC2S,O_WC2B};

struct ConvArgs { const void* p[36]; int cum[37]; int dst[36]; };

typedef __attribute__((ext_vector_type(8))) short short8;   // 8 bf16 (4 VGPRs)
typedef __attribute__((ext_vector_type(4))) float fragf4;   // MFMA C/D

__device__ __forceinline__ float sigf(float v){ return 1.0f/(1.0f+expf(-v)); }
__device__ __forceinline__ float hb2f(unsigned short h){ return __uint_as_float(((unsigned)h)<<16); }
__device__ __forceinline__ unsigned short f2hb(float v){
  __hip_bfloat16 hb = __float2bfloat16(v);
  return *reinterpret_cast<unsigned short*>(&hb);
}
__device__ __forceinline__ float loadx(const void* x, int flag, size_t idx){
  if (flag) return hb2f(((const unsigned short*)x)[idx]);
  return ((const float*)x)[idx];
}

// ---- kd: dtype probe. bf16 data -> ~all sane exponents; f32-misread -> ~62%.
__global__ void kd_detect(const void* x, int* flag){
  __shared__ int cnt[256];
  int t = threadIdx.x;
  const unsigned short* h = (const unsigned short*)x;
  int c = 0;
  for (int k=0;k<4;k++){
    unsigned short v = h[t*4+k];
    int e = (v>>7)&0xFF;
    c += (e==0 || (e>=97 && e<=157)) ? 1 : 0;
  }
  cnt[t] = c;
  __syncthreads();
  for (int s=128; s; s>>=1){ if (t<s) cnt[t]+=cnt[t+s]; __syncthreads(); }
  if (t==0) *flag = (cnt[0] >= 973) ? 1 : 0;
}

// ---- kc: convert all non-x inputs to f32 arena wf
__global__ void kc_convert(ConvArgs a, const int* flagp, float* wf){
  int flag = *flagp;
  int g = blockIdx.x*256 + threadIdx.x;
  if (g >= a.cum[36]) return;
  int i = 0;
  while (g >= a.cum[i+1]) i++;
  int local = g - a.cum[i];
  float v;
  if (flag) v = hb2f(((const unsigned short*)a.p[i])[local]);
  else      v = ((const float*)a.p[i])[local];
  wf[a.dst[i] + local] = v;
}

// ---- kw: bf16 copies of thc/phc/gxc weights for MFMA (lossless if input bf16)
__global__ void kw_wbf(const float* wf, unsigned short* wbf){
  int i = blockIdx.x*256 + threadIdx.x;
  if (i >= 3*IS*HW) return;
  int which = i/(IS*HW), r = i - which*(IS*HW);
  int off = which==0?O_THCW:(which==1?O_PHCW:O_GXCW);
  wbf[i] = f2hb(wf[off + r]);
}

// ---- k0: ws1_w [49,197] -> ws1t [197,49]
__global__ void k0_ws1t(const float* wf, float* ws1t){
  int i = blockIdx.x*256 + threadIdx.x;
  if (i >= 197*49) return;
  int o = i / 49, o2 = i - o*49;
  ws1t[i] = wf[O_WS1W + o2*197 + o];
}

// ---- k1: theta/phi projections [b,32,784]
__global__ void k1_proj(const void* x, const int* flagp, const float* wf,
                        float* theta, float* phi){
  int flag = *flagp;
  int idx = blockIdx.x*256 + threadIdx.x;    // 64*64*784 exact
  int p = idx % HW; int o = (idx/HW)&63; int b = idx/(HW*64);
  int grp = o >> 5, r = o & 31;
  const float* w = wf + O_THW + grp*4096 + r*CC;
  float acc = 0.f;
  if (flag){
    const unsigned short* xb = (const unsigned short*)x + (size_t)b*CC*HW + p;
    #pragma unroll 8
    for (int c=0;c<CC;c+=4){
      float4 wv = *(const float4*)(w+c);
      acc += wv.x*hb2f(xb[(c+0)*HW]) + wv.y*hb2f(xb[(c+1)*HW])
           + wv.z*hb2f(xb[(c+2)*HW]) + wv.w*hb2f(xb[(c+3)*HW]);
    }
  } else {
    const float* xb = (const float*)x + (size_t)b*CC*HW + p;
    #pragma unroll 8
    for (int c=0;c<CC;c+=4){
      float4 wv = *(const float4*)(w+c);
      acc += wv.x*xb[(c+0)*HW] + wv.y*xb[(c+1)*HW]
           + wv.z*xb[(c+2)*HW] + wv.w*xb[(c+3)*HW];
    }
  }
  float sc = wf[O_THS + grp*64 + r], sh = wf[O_THB + grp*64 + r];
  float v = fmaxf(sc*acc + sh, 0.f);
  float* dst = grp ? phi : theta;
  dst[((size_t)b*IC + r)*HW + p] = v;
}

// ---- k2: g_xs[b,p] = mean_r relu(gxs_s[r]*dot(gxs_w[r,:],x[b,:,p])+gxs_b[r])
__global__ void k2_gxs(const void* x, const int* flagp, const float* wf, float* g_xs){
  int flag = *flagp;
  int idx = blockIdx.x*256 + threadIdx.x;    // 64*784 exact
  int p = idx % HW, b = idx / HW;
  float acc[32];
  #pragma unroll
  for (int r=0;r<32;r++) acc[r]=0.f;
  for (int c0=0;c0<CC;c0+=32){
    float xv[32];
    if (flag){
      const unsigned short* xb = (const unsigned short*)x + (size_t)b*CC*HW + p;
      #pragma unroll
      for (int cc=0;cc<32;cc++) xv[cc] = hb2f(xb[(c0+cc)*HW]);
    } else {
      const float* xb = (const float*)x + (size_t)b*CC*HW + p;
      #pragma unroll
      for (int cc=0;cc<32;cc++) xv[cc] = xb[(c0+cc)*HW];
    }
    #pragma unroll
    for (int r=0;r<32;r++){
      const float* wrow = wf + O_GXSW + r*CC + c0;
      #pragma unroll
      for (int cc=0;cc<32;cc+=4){
        float4 wv = *(const float4*)(wrow+cc);
        acc[r] += wv.x*xv[cc]+wv.y*xv[cc+1]+wv.z*xv[cc+2]+wv.w*xv[cc+3];
      }
    }
  }
  float m = 0.f;
  #pragma unroll
  for (int r=0;r<32;r++) m += fmaxf(wf[O_GXSS+r]*acc[r]+wf[O_GXSB+r], 0.f);
  g_xs[idx] = m*(1.f/32.f);
}

// ---- k3 v2: Aphi[b,o,c] = sum_j ggs_w[o,j]*phi[b,c,j] ; Atheta with w2/theta
__global__ __launch_bounds__(64) void k3_afact(const float* wf, const float* theta,
                                               const float* phi,
                                               float* Aphi, float* Atheta){
  __shared__ __align__(16) float Wl[32*60];
  __shared__ __align__(16) float Sl[32*60];
  int t = threadIdx.x;                     // 64 threads
  int ot = blockIdx.x % 7;
  int b  = (blockIdx.x/7) & 63;
  int which = blockIdx.x / (7*64);
  const float* src = which ? theta : phi;
  float* dst = which ? Atheta : Aphi;
  const float* wbase = wf + O_GGSW + (which ? HW : 0);
  int o0 = ot*32;
  int oq = t & 7, cq = t >> 3;
  float acc[4][4];
  #pragma unroll
  for (int oo=0;oo<4;oo++)
    #pragma unroll
    for (int cc=0;cc<4;cc++) acc[oo][cc]=0.f;

  for (int ch=0; ch<14; ch++){
    int j0 = ch*56;
    __syncthreads();
    #pragma unroll
    for (int pass=0; pass<7; pass++){
      int i = pass*64 + t;                 // 448 quads each for W and S
      int row = i/14, jq = i - row*14;
      int o = o0 + row;
      float4 wv = make_float4(0.f,0.f,0.f,0.f);
      if (o < IS) wv = *(const float4*)(wbase + (size_t)o*(2*HW) + j0 + 4*jq);
      *(float4*)(Wl + row*60 + 4*jq) = wv;
      *(float4*)(Sl + row*60 + 4*jq) =
          *(const float4*)(src + ((size_t)b*IC + row)*HW + j0 + 4*jq);
    }
    __syncthreads();
    #pragma unroll
    for (int jq=0; jq<14; jq++){
      float4 w4[4], s4[4];
      #pragma unroll
      for (int oo=0;oo<4;oo++) w4[oo] = *(const float4*)(Wl + (oq+8*oo)*60 + 4*jq);
      #pragma unroll
      for (int cc=0;cc<4;cc++) s4[cc] = *(const float4*)(Sl + (cq+8*cc)*60 + 4*jq);
      #pragma unroll
      for (int oo=0;oo<4;oo++)
        #pragma unroll
        for (int cc=0;cc<4;cc++)
          acc[oo][cc] += w4[oo].x*s4[cc].x + w4[oo].y*s4[cc].y
                       + w4[oo].z*s4[cc].z + w4[oo].w*s4[cc].w;
    }
  }
  #pragma unroll
  for (int oo=0;oo<4;oo++){
    int o = o0 + oq + 8*oo;
    if (o >= IS) continue;
    #pragma unroll
    for (int cc=0;cc<4;cc++){
      int c = cq + 8*cc;
      dst[((size_t)b*IS + o)*IC + c] = acc[oo][cc];
    }
  }
}

// ---- k4 v5: fused Gs_joint + ws1 + ws2 + sigmoid + apply -> x1tp bf16 [b,c,p]
// Block = (b, 64-p tile), 4 waves; wave w owns o in [49w,49w+49); partial
// acc[49] reduced through LDS; wave 0 does the 49->1 epilogue; all waves
// apply a to the 128 channels (coalesced u16 stores).
__global__ __launch_bounds__(256,3) void k4_spatial(const void* x, const int* flagp,
    const float* wf, const float* theta, const float* phi,
    const float* Aphi, const float* Atheta,
    const float* g_xs, const float* ws1t, unsigned short* x1tp)
{
  __shared__ float pacc[4][DS][64];   // 49 KB
  __shared__ float ash[64];
  int flag = *flagp;
  int t = threadIdx.x;
  int w = t >> 6, lane = t & 63;
  int pt = blockIdx.x % 13;
  int b  = blockIdx.x / 13;           // block-uniform
  int p0 = pt*64;
  int p = p0 + lane;
  bool pval = (p < HW);
  int pc = pval ? p : (HW-1);
  float th[IC], ph[IC];
  #pragma unroll
  for (int c=0;c<IC;c++){
    th[c] = theta[((size_t)b*IC+c)*HW + pc];
    ph[c] = phi[((size_t)b*IC+c)*HW + pc];
  }
  float acc[DS];
  #pragma unroll
  for (int o2=0;o2<DS;o2++) acc[o2] = 0.f;
  const float* Ab = Aphi   + (size_t)b*IS*IC;
  const float* Tb = Atheta + (size_t)b*IS*IC;
  int obase = w*DS;
  for (int i=0;i<DS;i++){
    int o = obase + i;
    const float* ar = Ab + o*IC;
    const float* tr = Tb + o*IC;
    float g0=0.f,g1=0.f,g2=0.f,g3=0.f;
    #pragma unroll
    for (int c=0;c<IC;c+=4){
      g0 += ar[c+0]*th[c+0] + tr[c+0]*ph[c+0];
      g1 += ar[c+1]*th[c+1] + tr[c+1]*ph[c+1];
      g2 += ar[c+2]*th[c+2] + tr[c+2]*ph[c+2];
      g3 += ar[c+3]*th[c+3] + tr[c+3]*ph[c+3];
    }
    float g = fmaxf(wf[O_GGSS+o]*((g0+g1)+(g2+g3)) + wf[O_GGSB+o], 0.f);
    const float* wr = ws1t + (o+1)*DS;
    #pragma unroll
    for (int o2=0;o2<DS;o2++) acc[o2] += wr[o2]*g;
  }
  #pragma unroll
  for (int o2=0;o2<DS;o2++) pacc[w][o2][lane] = acc[o2];
  __syncthreads();
  if (w == 0){
    float gx = g_xs[b*HW + pc];
    float wys = 0.f;
    #pragma unroll
    for (int o2=0;o2<DS;o2++){
      float af = ((pacc[0][o2][lane] + pacc[1][o2][lane])
               +  (pacc[2][o2][lane] + pacc[3][o2][lane])) + ws1t[o2]*gx;
      float z = fmaxf(wf[O_WS1S+o2]*af + wf[O_WS1B+o2], 0.f);
      wys += wf[O_WS2W+o2]*z;
    }
    ash[lane] = sigf(wf[O_WS2S]*wys + wf[O_WS2B]);
  }
  __syncthreads();
  float a = ash[lane];
  if (!pval) return;
  unsigned short* dst = x1tp + (size_t)b*CC*HW + p;
  #pragma unroll 4
  for (int cc=0; cc<32; cc++){
    int c = w*32 + cc;
    float v = a*loadx(x, flag, (size_t)b*CC*HW + (size_t)c*HW + p);
    dst[(size_t)c*HW] = f2hb(v);
  }
}

// ---- k8 v2 (MFMA): out[b,s,c] = relu(sc*(sum_p W[s,p]*x1[b,p,c])+sh)
#define KST 40
__global__ __launch_bounds__(256,1) void k8_mfma(const unsigned short* wbf,
    const unsigned short* x1tp, const float* wf,
    float* thcp, float* phcp, float* gxcp)
{
  __shared__ __align__(16) unsigned short Al[208*KST];
  __shared__ __align__(16) unsigned short Bl[128*KST];
  int t = threadIdx.x;
  int b = blockIdx.x & 63;
  int which = blockIdx.x >> 6;
  const unsigned short* wsrc = wbf + (size_t)which*IS*HW;
  const unsigned short* xsrc = x1tp + (size_t)b*CC*HW;
  int lane = t & 63, w = t >> 6;
  int m16 = lane & 15, kq = lane >> 4;
  fragf4 acc[13][2];
  #pragma unroll
  for (int st=0; st<13; st++)
    #pragma unroll
    for (int ct=0; ct<2; ct++)
      #pragma unroll
      for (int r=0; r<4; r++) acc[st][ct][r] = 0.f;

  for (int kk=0; kk<25; kk++){
    int p0 = kk*32;
    __syncthreads();
    for (int i=t; i<208*4; i+=256){
      int row = i>>2, q = i&3;
      uint4 v = make_uint4(0u,0u,0u,0u);
      int p = p0 + q*8;
      if (row < IS && p+8 <= HW)
        v = *(const uint4*)(wsrc + (size_t)row*HW + p);
      *(uint4*)(Al + row*KST + q*8) = v;
    }
    for (int i=t; i<128*4; i+=256){
      int row = i>>2, q = i&3;
      uint4 v = make_uint4(0u,0u,0u,0u);
      int p = p0 + q*8;
      if (p+8 <= HW)
        v = *(const uint4*)(xsrc + (size_t)row*HW + p);
      *(uint4*)(Bl + row*KST + q*8) = v;
    }
    __syncthreads();
    short8 bfr[2];
    #pragma unroll
    for (int ct=0; ct<2; ct++){
      int n = (w*2+ct)*16 + m16;
      bfr[ct] = *(const short8*)(Bl + n*KST + kq*8);
    }
    #pragma unroll
    for (int st=0; st<13; st++){
      short8 af = *(const short8*)(Al + (st*16+m16)*KST + kq*8);
      acc[st][0] = __builtin_amdgcn_mfma_f32_16x16x32_bf16(af, bfr[0], acc[st][0], 0,0,0);
      acc[st][1] = __builtin_amdgcn_mfma_f32_16x16x32_bf16(af, bfr[1], acc[st][1], 0,0,0);
    }
  }
  const float* ss = wf + (which==0?O_THCS:(which==1?O_PHCS:O_GXCS));
  const float* sb = wf + (which==0?O_THCB:(which==1?O_PHCB:O_GXCB));
  float* dst = which==0?thcp:(which==1?phcp:gxcp);
  #pragma unroll
  for (int st=0; st<13; st++){
    #pragma unroll
    for (int r=0; r<4; r++){
      int s = st*16 + kq*4 + r;
      if (s >= IS) continue;
      float sc = ss[s], sh = sb[s];
      #pragma unroll
      for (int ct=0; ct<2; ct++){
        int c = (w*2+ct)*16 + m16;
        dst[((size_t)b*IS + s)*CC + c] = fmaxf(sc*acc[st][ct][r] + sh, 0.f);
      }
    }
  }
}

// ---- k9: Bph[b,s,o] = sum_j ggc_w[o,j]*phc[b,s,j]; Bth with w2/thc
__global__ void k9_bfact(const float* wf, const float* thcp, const float* phcp,
                         float* Bph, float* Bth)
{
  int gid = blockIdx.x*256 + threadIdx.x;    // 2*64*196*32 exact
  int o = gid & 31;
  int rest = gid >> 5;
  int s = rest % IS;
  int rb = rest / IS;           // [0,128)
  int b = rb & 63, which = rb >> 6;
  const float* src = which ? thcp : phcp;
  const float* wr = wf + O_GGCW + o*256 + which*CC;
  const float* sr = src + ((size_t)b*IS + s)*CC;
  float acc = 0.f;
  #pragma unroll 8
  for (int j=0;j<CC;j+=4){
    float4 wv = *(const float4*)(wr+j);
    float4 sv = *(const float4*)(sr+j);
    acc += wv.x*sv.x + wv.y*sv.y + wv.z*sv.z + wv.w*sv.w;
  }
  float* dst = which ? Bth : Bph;
  dst[((size_t)b*IS + s)*IC + o] = acc;
}

// ---- k10: fused Gc_joint + g_xc + wc1 + wc2 + sigmoid -> c_att[b,d]
__global__ void k10_catt(const float* wf, const float* thcp, const float* phcp,
                         const float* gxcp, const float* Bph, const float* Bth,
                         float* c_att)
{
  int idx = blockIdx.x*256 + threadIdx.x;    // 64*128 exact
  int d = idx & 127;
  int b = idx >> 7;
  float acc[IC];
  #pragma unroll
  for (int o=0;o<IC;o++) acc[o]=0.f;
  float gx = 0.f;
  const float* tb = thcp + (size_t)b*IS*CC + d;
  const float* pb = phcp + (size_t)b*IS*CC + d;
  const float* gb = gxcp + (size_t)b*IS*CC + d;
  for (int s=0;s<IS;s++){
    float tv = tb[(size_t)s*CC], pv = pb[(size_t)s*CC];
    gx += gb[(size_t)s*CC];
    const float* bp = Bph + ((size_t)b*IS+s)*IC;
    const float* bt = Bth + ((size_t)b*IS+s)*IC;
    #pragma unroll
    for (int o=0;o<IC;o++) acc[o] += bp[o]*tv + bt[o]*pv;
  }
  gx *= (1.f/196.f);
  #pragma unroll
  for (int o=0;o<IC;o++) acc[o] = fmaxf(wf[O_GGCS+o]*acc[o]+wf[O_GGCB+o], 0.f);
  float acc2 = 0.f;
  #pragma unroll
  for (int o2=0;o2<8;o2++){
    float tt = wf[O_WC1W + o2*33]*gx;
    #pragma unroll
    for (int o=0;o<IC;o++) tt += wf[O_WC1W + o2*33+1+o]*acc[o];
    float z = fmaxf(wf[O_WC1S+o2]*tt + wf[O_WC1B+o2], 0.f);
    acc2 += wf[O_WC2W+o2]*z;
  }
  c_att[idx] = sigf(wf[O_WC2S]*acc2 + wf[O_WC2B]);
}

// ---- k12 v2: out[b,c,p] = c_att[b,c]*x1tp[b,c,p] — pure streaming
__global__ void k12_final(const int* flagp, const unsigned int* x1tp2,
                          const float* c_att, void* out)
{
  int i = blockIdx.x*256 + threadIdx.x;      // over BB*CC*HW/2 uints, exact
  int flag = *flagp;
  unsigned int v = x1tp2[i];
  float a = c_att[i/392];                    // 392 uints per (b,c) row
  float v0 = a*hb2f((unsigned short)(v & 0xffff));
  float v1 = a*hb2f((unsigned short)(v >> 16));
  if (flag){
    ((unsigned int*)out)[i] = (unsigned)f2hb(v0) | ((unsigned)f2hb(v1)<<16);
  } else {
    ((float*)out)[2*i+0] = v0;
    ((float*)out)[2*i+1] = v1;
  }
}

extern "C" void kernel_launch(void* const* d_in, const int* in_sizes, int n_in,
                              void* d_out, int out_size, void* d_ws, size_t ws_size,
                              hipStream_t stream)
{
  const void* x = d_in[0];

  float* W = (float*)d_ws;
  int*   flag  = (int*)W;                    // W[0..63] reserved
  float* wf    = W + 64;                     // 800768
  float* theta = wf + WF_TOTAL;              // 1605632
  float* phi   = theta + 1605632;            // 1605632
  float* g_xs  = phi + 1605632;              // 50176
  float* Aphi  = g_xs + 50176;               // 401408
  float* Atheta= Aphi + 401408;              // 401408
  unsigned short* x1tp = (unsigned short*)(Atheta + 401408); // 6422528 u16 = 3211264 f32 slots
  float* thcp  = Atheta + 401408 + 3211264;  // 1605632
  float* phcp  = thcp + 1605632;             // 1605632
  float* gxcp  = phcp + 1605632;             // 1605632
  float* Bph   = gxcp + 1605632;             // 401408
  float* Bth   = Bph + 401408;               // 401408
  float* ws1t  = Bth + 401408;               // 9664
  float* c_att = ws1t + 9664;                // 8192
  unsigned short* wbf = (unsigned short*)(c_att + 8192);  // 460992 u16 (~53.2 MiB total)

  ConvArgs ca;
  ca.cum[0] = 0;
  for (int i=0;i<36;i++){
    ca.p[i] = d_in[i+1];
    ca.cum[i+1] = ca.cum[i] + SRC_SIZES[i];
    ca.dst[i] = DST_OFF[i];
  }

  kd_detect<<<1, 256, 0, stream>>>(x, flag);
  kc_convert<<<(800716+255)/256, 256, 0, stream>>>(ca, flag, wf);
  kw_wbf<<<(3*IS*HW+255)/256, 256, 0, stream>>>(wf, wbf);
  k0_ws1t<<<(197*49+255)/256, 256, 0, stream>>>(wf, ws1t);
  k1_proj<<<(BB*64*HW)/256, 256, 0, stream>>>(x, flag, wf, theta, phi);
  k2_gxs<<<(BB*HW)/256, 256, 0, stream>>>(x, flag, wf, g_xs);
  k3_afact<<<2*64*7, 64, 0, stream>>>(wf, theta, phi, Aphi, Atheta);
  k4_spatial<<<64*13, 256, 0, stream>>>(x, flag, wf, theta, phi, Aphi, Atheta,
      g_xs, ws1t, x1tp);
  k8_mfma<<<3*64, 256, 0, stream>>>(wbf, x1tp, wf, thcp, phcp, gxcp);
  k9_bfact<<<(2*BB*IS*IC)/256, 256, 0, stream>>>(wf, thcp, phcp, Bph, Bth);
  k10_catt<<<(BB*CC)/256, 256, 0, stream>>>(wf, thcp, phcp, gxcp, Bph, Bth, c_att);
  k12_final<<<(BB*CC*HW/2)/256, 256, 0, stream>>>(flag, (const unsigned int*)x1tp,
      c_att, d_out);
}

// Round 7
// 678.809 us; speedup vs baseline: 1.2961x; 1.2961x over previous
//
#include <hip/hip_runtime.h>
#include <hip/hip_bf16.h>
#include <math.h>

// RGA module: B=64, C=128, HW=784, IC=32, IS=196, DS=49, DC=8.
// Rank-32 factorization removes Gs [b,784,784] and Gc [b,128,128] entirely.
// R5: k8 channel projections on MFMA bf16.
// R7: k4 spatial chain (G = A_all@S, Y = W1aug@[gx;relu(bn(G))]) fully on MFMA,
//     fused with sigmoid + apply in one kernel (LDS union, 4 barriers).

#define BB 64
#define CC 128
#define HW 784
#define IC 32
#define IS 196
#define DS 49

// ---- wf (converted f32 inputs) offsets, padded to 4-float alignment ----
#define O_THW 0
#define O_PHW 4096
#define O_GGSW 8192
#define O_GXSW 315520
#define O_WS1W 319616
#define O_WS2W 329272
#define O_THCW 329324
#define O_PHCW 482988
#define O_GGCW 636652
#define O_GXCW 644844
#define O_WC1W 798508
#define O_WC2W 798772
#define O_THS 798780
#define O_THB 798812
#define O_PHS 798844
#define O_PHB 798876
#define O_GGSS 798908
#define O_GGSB 799104
#define O_GXSS 799300
#define O_GXSB 799332
#define O_WS1S 799364
#define O_WS1B 799416
#define O_WS2S 799468
#define O_WS2B 799472
#define O_THCS 799476
#define O_THCB 799672
#define O_PHCS 799868
#define O_PHCB 800064
#define O_GGCS 800260
#define O_GGCB 800292
#define O_GXCS 800324
#define O_GXCB 800520
#define O_WC1S 800716
#define O_WC1B 800724
#define O_WC2S 800732
#define O_WC2B 800736
#define WF_TOTAL 800768

static const int SRC_SIZES[36] = {
  4096,4096,307328,4096,9653,49,153664,153664,8192,153664,264,8,
  32,32,32,32,196,196,32,32,49,49,1,1,196,196,196,196,32,32,196,196,8,8,1,1};
static const int DST_OFF[36] = {
  O_THW,O_PHW,O_GGSW,O_GXSW,O_WS1W,O_WS2W,O_THCW,O_PHCW,O_GGCW,O_GXCW,O_WC1W,O_WC2W,
  O_THS,O_THB,O_PHS,O_PHB,O_GGSS,O_GGSB,O_GXSS,O_GXSB,O_WS1S,O_WS1B,O_WS2S,O_WS2B,
  O_THCS,O_THCB,O_PHCS,O_PHCB,O_GGCS,O_GGCB,O_GXCS,O_GXCB,O_WC1S,O_WC1B,O_WC2S,O_WC2B};

struct ConvArgs { const void* p[36]; int cum[37]; int dst[36]; };

typedef __attribute__((ext_vector_type(8))) short short8;   // 8 bf16 (4 VGPRs)
typedef __attribute__((ext_vector_type(4))) float fragf4;   // MFMA C/D

union FragU { unsigned int w[4]; short8 s8; };

__device__ __forceinline__ float sigf(float v){ return 1.0f/(1.0f+expf(-v)); }
__device__ __forceinline__ float hb2f(unsigned short h){ return __uint_as_float(((unsigned)h)<<16); }
__device__ __forceinline__ unsigned short f2hb(float v){
  __hip_bfloat16 hb = __float2bfloat16(v);
  return *reinterpret_cast<unsigned short*>(&hb);
}
__device__ __forceinline__ float loadx(const void* x, int flag, size_t idx){
  if (flag) return hb2f(((const unsigned short*)x)[idx]);
  return ((const float*)x)[idx];
}

// ---- kd: dtype probe. bf16 data -> ~all sane exponents; f32-misread -> ~62%.
__global__ void kd_detect(const void* x, int* flag){
  __shared__ int cnt[256];
  int t = threadIdx.x;
  const unsigned short* h = (const unsigned short*)x;
  int c = 0;
  for (int k=0;k<4;k++){
    unsigned short v = h[t*4+k];
    int e = (v>>7)&0xFF;
    c += (e==0 || (e>=97 && e<=157)) ? 1 : 0;
  }
  cnt[t] = c;
  __syncthreads();
  for (int s=128; s; s>>=1){ if (t<s) cnt[t]+=cnt[t+s]; __syncthreads(); }
  if (t==0) *flag = (cnt[0] >= 973) ? 1 : 0;
}

// ---- kc: convert all non-x inputs to f32 arena wf
__global__ void kc_convert(ConvArgs a, const int* flagp, float* wf){
  int flag = *flagp;
  int g = blockIdx.x*256 + threadIdx.x;
  if (g >= a.cum[36]) return;
  int i = 0;
  while (g >= a.cum[i+1]) i++;
  int local = g - a.cum[i];
  float v;
  if (flag) v = hb2f(((const unsigned short*)a.p[i])[local]);
  else      v = ((const float*)a.p[i])[local];
  wf[a.dst[i] + local] = v;
}

// ---- kw: bf16 copies of thc/phc/gxc weights for MFMA (lossless if input bf16)
__global__ void kw_wbf(const float* wf, unsigned short* wbf){
  int i = blockIdx.x*256 + threadIdx.x;
  if (i >= 3*IS*HW) return;
  int which = i/(IS*HW), r = i - which*(IS*HW);
  int off = which==0?O_THCW:(which==1?O_PHCW:O_GXCW);
  wbf[i] = f2hb(wf[off + r]);
}

// ---- k0: ws1bf [64][224] bf16 (zero-padded W1aug: col0 = gx weight)
__global__ void k0_ws1bf(const float* wf, unsigned int* ws1bf32){
  int i = blockIdx.x*256 + threadIdx.x;      // 64*112 u32
  if (i >= 64*112) return;
  int o2 = i/112, k2 = i - o2*112;
  int k = k2*2;
  float v0 = (o2<DS && k<197)   ? wf[O_WS1W + o2*197 + k]   : 0.f;
  float v1 = (o2<DS && k+1<197) ? wf[O_WS1W + o2*197 + k+1] : 0.f;
  ws1bf32[i] = (unsigned)f2hb(v0) | ((unsigned)f2hb(v1)<<16);
}

// ---- k1: theta/phi projections [b,32,784] f32
__global__ void k1_proj(const void* x, const int* flagp, const float* wf,
                        float* theta, float* phi){
  int flag = *flagp;
  int idx = blockIdx.x*256 + threadIdx.x;    // 64*64*784 exact
  int p = idx % HW; int o = (idx/HW)&63; int b = idx/(HW*64);
  int grp = o >> 5, r = o & 31;
  const float* w = wf + O_THW + grp*4096 + r*CC;
  float acc = 0.f;
  if (flag){
    const unsigned short* xb = (const unsigned short*)x + (size_t)b*CC*HW + p;
    #pragma unroll 8
    for (int c=0;c<CC;c+=4){
      float4 wv = *(const float4*)(w+c);
      acc += wv.x*hb2f(xb[(c+0)*HW]) + wv.y*hb2f(xb[(c+1)*HW])
           + wv.z*hb2f(xb[(c+2)*HW]) + wv.w*hb2f(xb[(c+3)*HW]);
    }
  } else {
    const float* xb = (const float*)x + (size_t)b*CC*HW + p;
    #pragma unroll 8
    for (int c=0;c<CC;c+=4){
      float4 wv = *(const float4*)(w+c);
      acc += wv.x*xb[(c+0)*HW] + wv.y*xb[(c+1)*HW]
           + wv.z*xb[(c+2)*HW] + wv.w*xb[(c+3)*HW];
    }
  }
  float sc = wf[O_THS + grp*64 + r], sh = wf[O_THB + grp*64 + r];
  float v = fmaxf(sc*acc + sh, 0.f);
  float* dst = grp ? phi : theta;
  dst[((size_t)b*IC + r)*HW + p] = v;
}

// ---- k2: g_xs[b,p] = mean_r relu(gxs_s[r]*dot(gxs_w[r,:],x[b,:,p])+gxs_b[r])
__global__ void k2_gxs(const void* x, const int* flagp, const float* wf, float* g_xs){
  int flag = *flagp;
  int idx = blockIdx.x*256 + threadIdx.x;    // 64*784 exact
  int p = idx % HW, b = idx / HW;
  float acc[32];
  #pragma unroll
  for (int r=0;r<32;r++) acc[r]=0.f;
  for (int c0=0;c0<CC;c0+=32){
    float xv[32];
    if (flag){
      const unsigned short* xb = (const unsigned short*)x + (size_t)b*CC*HW + p;
      #pragma unroll
      for (int cc=0;cc<32;cc++) xv[cc] = hb2f(xb[(c0+cc)*HW]);
    } else {
      const float* xb = (const float*)x + (size_t)b*CC*HW + p;
      #pragma unroll
      for (int cc=0;cc<32;cc++) xv[cc] = xb[(c0+cc)*HW];
    }
    #pragma unroll
    for (int r=0;r<32;r++){
      const float* wrow = wf + O_GXSW + r*CC + c0;
      #pragma unroll
      for (int cc=0;cc<32;cc+=4){
        float4 wv = *(const float4*)(wrow+cc);
        acc[r] += wv.x*xv[cc]+wv.y*xv[cc+1]+wv.z*xv[cc+2]+wv.w*xv[cc+3];
      }
    }
  }
  float m = 0.f;
  #pragma unroll
  for (int r=0;r<32;r++) m += fmaxf(wf[O_GXSS+r]*acc[r]+wf[O_GXSB+r], 0.f);
  g_xs[idx] = m*(1.f/32.f);
}

// ---- k3 v2: Aphi[b,o,c] = sum_j ggs_w[o,j]*phi[b,c,j] ; Atheta with w2/theta
__global__ __launch_bounds__(64) void k3_afact(const float* wf, const float* theta,
                                               const float* phi,
                                               float* Aphi, float* Atheta){
  __shared__ __align__(16) float Wl[32*60];
  __shared__ __align__(16) float Sl[32*60];
  int t = threadIdx.x;                     // 64 threads
  int ot = blockIdx.x % 7;
  int b  = (blockIdx.x/7) & 63;
  int which = blockIdx.x / (7*64);
  const float* src = which ? theta : phi;
  float* dst = which ? Atheta : Aphi;
  const float* wbase = wf + O_GGSW + (which ? HW : 0);
  int o0 = ot*32;
  int oq = t & 7, cq = t >> 3;
  float acc[4][4];
  #pragma unroll
  for (int oo=0;oo<4;oo++)
    #pragma unroll
    for (int cc=0;cc<4;cc++) acc[oo][cc]=0.f;

  for (int ch=0; ch<14; ch++){
    int j0 = ch*56;
    __syncthreads();
    #pragma unroll
    for (int pass=0; pass<7; pass++){
      int i = pass*64 + t;                 // 448 quads each for W and S
      int row = i/14, jq = i - row*14;
      int o = o0 + row;
      float4 wv = make_float4(0.f,0.f,0.f,0.f);
      if (o < IS) wv = *(const float4*)(wbase + (size_t)o*(2*HW) + j0 + 4*jq);
      *(float4*)(Wl + row*60 + 4*jq) = wv;
      *(float4*)(Sl + row*60 + 4*jq) =
          *(const float4*)(src + ((size_t)b*IC + row)*HW + j0 + 4*jq);
    }
    __syncthreads();
    #pragma unroll
    for (int jq=0; jq<14; jq++){
      float4 w4[4], s4[4];
      #pragma unroll
      for (int oo=0;oo<4;oo++) w4[oo] = *(const float4*)(Wl + (oq+8*oo)*60 + 4*jq);
      #pragma unroll
      for (int cc=0;cc<4;cc++) s4[cc] = *(const float4*)(Sl + (cq+8*cc)*60 + 4*jq);
      #pragma unroll
      for (int oo=0;oo<4;oo++)
        #pragma unroll
        for (int cc=0;cc<4;cc++)
          acc[oo][cc] += w4[oo].x*s4[cc].x + w4[oo].y*s4[cc].y
                       + w4[oo].z*s4[cc].z + w4[oo].w*s4[cc].w;
    }
  }
  #pragma unroll
  for (int oo=0;oo<4;oo++){
    int o = o0 + oq + 8*oo;
    if (o >= IS) continue;
    #pragma unroll
    for (int cc=0;cc<4;cc++){
      int c = cq + 8*cc;
      dst[((size_t)b*IS + o)*IC + c] = acc[oo][cc];
    }
  }
}

// ---- k4 v6 (MFMA): fused spatial chain per (b, 64-p tile).
// Phase1: Gt[p][o] = S^T @ A_all^T via MFMA (K=64). Phase2: bn+relu -> LDS
// (augmented col0 = g_xs). Phase3: Yt[p][o2] = Gt @ ws1bf^T (K=224, zero-pad).
// Phase4: ws1-bn-relu + ws2 dot + shfl reduce + sigmoid. Phase5: apply to x.
#define ALS 33    // Al/Sl u32 stride
#define GTS 113   // Gt u32 stride (226 u16)
union K4Sh {
  struct { unsigned int Al[208*ALS]; unsigned int Sl[64*ALS]; } s1;
  unsigned int Gt[64*GTS];
};
__global__ __launch_bounds__(256,3) void k4_mfma(const void* x, const int* flagp,
    const float* wf, const float* theta, const float* phi,
    const float* Aphi, const float* Atheta, const float* g_xs,
    const unsigned int* ws1bf32, unsigned short* x1tp)
{
  __shared__ K4Sh sh;
  __shared__ float ash[64];
  int flag = *flagp;
  int t = threadIdx.x;
  int pt = blockIdx.x % 13, b = blockIdx.x / 13;
  int p0 = pt*64;
  int lane = t & 63, w = t >> 6;
  int col = lane & 15, kq = lane >> 4;

  // stage Al[o][cp]: A_all = [Aphi|Atheta] rows o, packed bf16 pairs
  const float* Ab = Aphi   + (size_t)b*IS*IC;
  const float* Tb = Atheta + (size_t)b*IS*IC;
  for (int i=t; i<208*32; i+=256){
    int o = i>>5, cp = i&31;
    unsigned int v = 0u;
    if (o < IS){
      const float* src = (cp<16 ? Ab : Tb) + o*IC + (cp&15)*2;
      v = (unsigned)f2hb(src[0]) | ((unsigned)f2hb(src[1])<<16);
    }
    sh.s1.Al[o*ALS + cp] = v;
  }
  // stage Sl[pp][c2]: S = stack(theta,phi) cols p0..p0+63, packed bf16 pairs
  for (int i=t; i<32*64; i+=256){
    int c2 = i>>6, pp = i&63;
    int p = p0+pp;
    unsigned int v = 0u;
    if (p < HW){
      int c = c2*2;
      const float* s0 = (c<32   ? theta : phi) + ((size_t)b*IC + (c&31))*HW + p;
      const float* s1 = (c+1<32 ? theta : phi) + ((size_t)b*IC + ((c+1)&31))*HW + p;
      v = (unsigned)f2hb(*s0) | ((unsigned)f2hb(*s1)<<16);
    }
    sh.s1.Sl[pp*ALS + c2] = v;
  }
  __syncthreads();

  // phase 1: acc1[nt] = Gt tile [m=p=w*16+.., n=o=nt*16+..], K=64
  fragf4 acc1[13];
  #pragma unroll
  for (int nt=0; nt<13; nt++)
    #pragma unroll
    for (int r=0;r<4;r++) acc1[nt][r] = 0.f;
  #pragma unroll
  for (int kk=0; kk<2; kk++){
    FragU af;
    #pragma unroll
    for (int q=0;q<4;q++) af.w[q] = sh.s1.Sl[(w*16+col)*ALS + kk*16 + kq*4 + q];
    #pragma unroll
    for (int nt=0; nt<13; nt++){
      FragU bf;
      #pragma unroll
      for (int q=0;q<4;q++) bf.w[q] = sh.s1.Al[(nt*16+col)*ALS + kk*16 + kq*4 + q];
      acc1[nt] = __builtin_amdgcn_mfma_f32_16x16x32_bf16(af.s8, bf.s8, acc1[nt], 0,0,0);
    }
  }
  __syncthreads();   // Al/Sl dead; Gt aliases them

  // phase 2: bn+relu -> Gt bf16 [p][1+o]; col0 = gx; zero pad k=208..225
  unsigned short* Gt16 = (unsigned short*)sh.Gt;
  for (int i=t; i<64*9; i+=256){
    int pp = i/9, q = i - pp*9;
    sh.Gt[pp*GTS + 104 + q] = 0u;
  }
  if (t < 64){
    int p = p0 + t;
    float gx = (p < HW) ? g_xs[b*HW + p] : 0.f;
    Gt16[t*226 + 0] = f2hb(gx);
  }
  #pragma unroll
  for (int nt=0; nt<13; nt++){
    int o = nt*16 + col;
    float sc = wf[O_GGSS + o], shf = wf[O_GGSB + o];  // o>=196 reads adjacent wf: inert
    #pragma unroll
    for (int r=0;r<4;r++){
      int pp = w*16 + kq*4 + r;
      float g = fmaxf(sc*acc1[nt][r] + shf, 0.f);
      Gt16[pp*226 + 1 + o] = f2hb(g);
    }
  }
  __syncthreads();

  // phase 3: acc2[nt] = Yt tile [m=p, n=o2=nt*16+..], K=224
  fragf4 acc2[4];
  #pragma unroll
  for (int nt=0; nt<4; nt++)
    #pragma unroll
    for (int r=0;r<4;r++) acc2[nt][r] = 0.f;
  #pragma unroll
  for (int kk=0; kk<7; kk++){
    FragU af;
    #pragma unroll
    for (int q=0;q<4;q++) af.w[q] = sh.Gt[(w*16+col)*GTS + kk*16 + kq*4 + q];
    #pragma unroll
    for (int nt=0; nt<4; nt++){
      FragU bf;
      #pragma unroll
      for (int q=0;q<4;q++) bf.w[q] = ws1bf32[(nt*16+col)*112 + kk*16 + kq*4 + q];
      acc2[nt] = __builtin_amdgcn_mfma_f32_16x16x32_bf16(af.s8, bf.s8, acc2[nt], 0,0,0);
    }
  }

  // phase 4: z = relu(ws1_s*Y+ws1_b); wys = sum ws2_w*z; reduce over col; sigmoid
  float wys[4] = {0.f,0.f,0.f,0.f};
  #pragma unroll
  for (int nt=0; nt<4; nt++){
    int o2 = nt*16 + col;
    bool vd = (o2 < DS);
    float s1 = vd ? wf[O_WS1S+o2] : 0.f;
    float b1 = vd ? wf[O_WS1B+o2] : 0.f;
    float w2 = vd ? wf[O_WS2W+o2] : 0.f;
    #pragma unroll
    for (int r=0;r<4;r++){
      float z = fmaxf(s1*acc2[nt][r] + b1, 0.f);
      wys[r] += w2*z;
    }
  }
  #pragma unroll
  for (int m=1; m<16; m<<=1){
    #pragma unroll
    for (int r=0;r<4;r++) wys[r] += __shfl_xor(wys[r], m, 16);
  }
  if (col == 0){
    float s2 = wf[O_WS2S], b2 = wf[O_WS2B];
    #pragma unroll
    for (int r=0;r<4;r++){
      int pp = w*16 + kq*4 + r;
      ash[pp] = sigf(s2*wys[r] + b2);
    }
  }
  __syncthreads();

  // phase 5: x1tp[b][c][p] = bf16(a[p]*x[b][c][p])
  for (int i=t; i<CC*64; i+=256){
    int c = i>>6, pp = i&63;
    int p = p0 + pp;
    if (p < HW){
      float v = ash[pp]*loadx(x, flag, (size_t)b*CC*HW + (size_t)c*HW + p);
      x1tp[(size_t)b*CC*HW + (size_t)c*HW + p] = f2hb(v);
    }
  }
}

// ---- k8 v2 (MFMA): out[b,s,c] = relu(sc*(sum_p W[s,p]*x1[b,p,c])+sh)
#define KST 40
__global__ __launch_bounds__(256,1) void k8_mfma(const unsigned short* wbf,
    const unsigned short* x1tp, const float* wf,
    float* thcp, float* phcp, float* gxcp)
{
  __shared__ __align__(16) unsigned short Al[208*KST];
  __shared__ __align__(16) unsigned short Bl[128*KST];
  int t = threadIdx.x;
  int b = blockIdx.x & 63;
  int which = blockIdx.x >> 6;
  const unsigned short* wsrc = wbf + (size_t)which*IS*HW;
  const unsigned short* xsrc = x1tp + (size_t)b*CC*HW;
  int lane = t & 63, w = t >> 6;
  int m16 = lane & 15, kq = lane >> 4;
  fragf4 acc[13][2];
  #pragma unroll
  for (int st=0; st<13; st++)
    #pragma unroll
    for (int ct=0; ct<2; ct++)
      #pragma unroll
      for (int r=0; r<4; r++) acc[st][ct][r] = 0.f;

  for (int kk=0; kk<25; kk++){
    int p0 = kk*32;
    __syncthreads();
    for (int i=t; i<208*4; i+=256){
      int row = i>>2, q = i&3;
      uint4 v = make_uint4(0u,0u,0u,0u);
      int p = p0 + q*8;
      if (row < IS && p+8 <= HW)
        v = *(const uint4*)(wsrc + (size_t)row*HW + p);
      *(uint4*)(Al + row*KST + q*8) = v;
    }
    for (int i=t; i<128*4; i+=256){
      int row = i>>2, q = i&3;
      uint4 v = make_uint4(0u,0u,0u,0u);
      int p = p0 + q*8;
      if (p+8 <= HW)
        v = *(const uint4*)(xsrc + (size_t)row*HW + p);
      *(uint4*)(Bl + row*KST + q*8) = v;
    }
    __syncthreads();
    short8 bfr[2];
    #pragma unroll
    for (int ct=0; ct<2; ct++){
      int n = (w*2+ct)*16 + m16;
      bfr[ct] = *(const short8*)(Bl + n*KST + kq*8);
    }
    #pragma unroll
    for (int st=0; st<13; st++){
      short8 af = *(const short8*)(Al + (st*16+m16)*KST + kq*8);
      acc[st][0] = __builtin_amdgcn_mfma_f32_16x16x32_bf16(af, bfr[0], acc[st][0], 0,0,0);
      acc[st][1] = __builtin_amdgcn_mfma_f32_16x16x32_bf16(af, bfr[1], acc[st][1], 0,0,0);
    }
  }
  const float* ss = wf + (which==0?O_THCS:(which==1?O_PHCS:O_GXCS));
  const float* sb = wf + (which==0?O_THCB:(which==1?O_PHCB:O_GXCB));
  float* dst = which==0?thcp:(which==1?phcp:gxcp);
  #pragma unroll
  for (int st=0; st<13; st++){
    #pragma unroll
    for (int r=0; r<4; r++){
      int s = st*16 + kq*4 + r;
      if (s >= IS) continue;
      float sc = ss[s], sh = sb[s];
      #pragma unroll
      for (int ct=0; ct<2; ct++){
        int c = (w*2+ct)*16 + m16;
        dst[((size_t)b*IS + s)*CC + c] = fmaxf(sc*acc[st][ct][r] + sh, 0.f);
      }
    }
  }
}

// ---- k9: Bph[b,s,o] = sum_j ggc_w[o,j]*phc[b,s,j]; Bth with w2/thc
__global__ void k9_bfact(const float* wf, const float* thcp, const float* phcp,
                         float* Bph, float* Bth)
{
  int gid = blockIdx.x*256 + threadIdx.x;    // 2*64*196*32 exact
  int o = gid & 31;
  int rest = gid >> 5;
  int s = rest % IS;
  int rb = rest / IS;           // [0,128)
  int b = rb & 63, which = rb >> 6;
  const float* src = which ? thcp : phcp;
  const float* wr = wf + O_GGCW + o*256 + which*CC;
  const float* sr = src + ((size_t)b*IS + s)*CC;
  float acc = 0.f;
  #pragma unroll 8
  for (int j=0;j<CC;j+=4){
    float4 wv = *(const float4*)(wr+j);
    float4 sv = *(const float4*)(sr+j);
    acc += wv.x*sv.x + wv.y*sv.y + wv.z*sv.z + wv.w*sv.w;
  }
  float* dst = which ? Bth : Bph;
  dst[((size_t)b*IS + s)*IC + o] = acc;
}

// ---- k10: fused Gc_joint + g_xc + wc1 + wc2 + sigmoid -> c_att[b,d]
__global__ void k10_catt(const float* wf, const float* thcp, const float* phcp,
                         const float* gxcp, const float* Bph, const float* Bth,
                         float* c_att)
{
  int idx = blockIdx.x*256 + threadIdx.x;    // 64*128 exact
  int d = idx & 127;
  int b = idx >> 7;
  float acc[IC];
  #pragma unroll
  for (int o=0;o<IC;o++) acc[o]=0.f;
  float gx = 0.f;
  const float* tb = thcp + (size_t)b*IS*CC + d;
  const float* pb = phcp + (size_t)b*IS*CC + d;
  const float* gb = gxcp + (size_t)b*IS*CC + d;
  for (int s=0;s<IS;s++){
    float tv = tb[(size_t)s*CC], pv = pb[(size_t)s*CC];
    gx += gb[(size_t)s*CC];
    const float* bp = Bph + ((size_t)b*IS+s)*IC;
    const float* bt = Bth + ((size_t)b*IS+s)*IC;
    #pragma unroll
    for (int o=0;o<IC;o++) acc[o] += bp[o]*tv + bt[o]*pv;
  }
  gx *= (1.f/196.f);
  #pragma unroll
  for (int o=0;o<IC;o++) acc[o] = fmaxf(wf[O_GGCS+o]*acc[o]+wf[O_GGCB+o], 0.f);
  float acc2 = 0.f;
  #pragma unroll
  for (int o2=0;o2<8;o2++){
    float tt = wf[O_WC1W + o2*33]*gx;
    #pragma unroll
    for (int o=0;o<IC;o++) tt += wf[O_WC1W + o2*33+1+o]*acc[o];
    float z = fmaxf(wf[O_WC1S+o2]*tt + wf[O_WC1B+o2], 0.f);
    acc2 += wf[O_WC2W+o2]*z;
  }
  c_att[idx] = sigf(wf[O_WC2S]*acc2 + wf[O_WC2B]);
}

// ---- k12 v2: out[b,c,p] = c_att[b,c]*x1tp[b,c,p] — pure streaming
__global__ void k12_final(const int* flagp, const unsigned int* x1tp2,
                          const float* c_att, void* out)
{
  int i = blockIdx.x*256 + threadIdx.x;      // over BB*CC*HW/2 uints, exact
  int flag = *flagp;
  unsigned int v = x1tp2[i];
  float a = c_att[i/392];                    // 392 uints per (b,c) row
  float v0 = a*hb2f((unsigned short)(v & 0xffff));
  float v1 = a*hb2f((unsigned short)(v >> 16));
  if (flag){
    ((unsigned int*)out)[i] = (unsigned)f2hb(v0) | ((unsigned)f2hb(v1)<<16);
  } else {
    ((float*)out)[2*i+0] = v0;
    ((float*)out)[2*i+1] = v1;
  }
}

extern "C" void kernel_launch(void* const* d_in, const int* in_sizes, int n_in,
                              void* d_out, int out_size, void* d_ws, size_t ws_size,
                              hipStream_t stream)
{
  const void* x = d_in[0];

  float* W = (float*)d_ws;
  int*   flag  = (int*)W;                    // W[0..63] reserved
  float* wf    = W + 64;                     // 800768
  float* theta = wf + WF_TOTAL;              // 1605632
  float* phi   = theta + 1605632;            // 1605632
  float* g_xs  = phi + 1605632;              // 50176
  float* Aphi  = g_xs + 50176;               // 401408
  float* Atheta= Aphi + 401408;              // 401408
  unsigned short* x1tp = (unsigned short*)(Atheta + 401408); // 6422528 u16 = 3211264 f32 slots
  float* thcp  = Atheta + 401408 + 3211264;  // 1605632
  float* phcp  = thcp + 1605632;             // 1605632
  float* gxcp  = phcp + 1605632;             // 1605632
  float* Bph   = gxcp + 1605632;             // 401408
  float* Bth   = Bph + 401408;               // 401408
  unsigned int* ws1bf32 = (unsigned int*)(Bth + 401408);  // 7168 u32 (slot 9664)
  float* c_att = (float*)(ws1bf32) + 9664;   // 8192
  unsigned short* wbf = (unsigned short*)(c_att + 8192);  // 460992 u16 (~53.2 MiB total)

  ConvArgs ca;
  ca.cum[0] = 0;
  for (int i=0;i<36;i++){
    ca.p[i] = d_in[i+1];
    ca.cum[i+1] = ca.cum[i] + SRC_SIZES[i];
    ca.dst[i] = DST_OFF[i];
  }

  kd_detect<<<1, 256, 0, stream>>>(x, flag);
  kc_convert<<<(800716+255)/256, 256, 0, stream>>>(ca, flag, wf);
  kw_wbf<<<(3*IS*HW+255)/256, 256, 0, stream>>>(wf, wbf);
  k0_ws1bf<<<(64*112+255)/256, 256, 0, stream>>>(wf, ws1bf32);
  k1_proj<<<(BB*64*HW)/256, 256, 0, stream>>>(x, flag, wf, theta, phi);
  k2_gxs<<<(BB*HW)/256, 256, 0, stream>>>(x, flag, wf, g_xs);
  k3_afact<<<2*64*7, 64, 0, stream>>>(wf, theta, phi, Aphi, Atheta);
  k4_mfma<<<64*13, 256, 0, stream>>>(x, flag, wf, theta, phi, Aphi, Atheta,
      g_xs, ws1bf32, x1tp);
  k8_mfma<<<3*64, 256, 0, stream>>>(wbf, x1tp, wf, thcp, phcp, gxcp);
  k9_bfact<<<(2*BB*IS*IC)/256, 256, 0, stream>>>(wf, thcp, phcp, Bph, Bth);
  k10_catt<<<(BB*CC)/256, 256, 0, stream>>>(wf, thcp, phcp, gxcp, Bph, Bth, c_att);
  k12_final<<<(BB*CC*HW/2)/256, 256, 0, stream>>>(flag, (const unsigned int*)x1tp,
      c_att, d_out);
}

// Round 8
// 559.959 us; speedup vs baseline: 1.5712x; 1.2122x over previous
//
#include <hip/hip_runtime.h>
#include <hip/hip_bf16.h>
#include <math.h>

// RGA module: B=64, C=128, HW=784, IC=32, IS=196, DS=49, DC=8.
// Rank-32 factorization removes Gs [b,784,784] and Gc [b,128,128] entirely.
// R5: k8 on MFMA. R7: k4 spatial chain fully on MFMA.
// R8: k10 split into s-chunk partials (896 blocks) + reduce, fixing 0.125
//     waves/SIMD latency stall; partials reuse dead theta/phi region.

#define BB 64
#define CC 128
#define HW 784
#define IC 32
#define IS 196
#define DS 49

// ---- wf (converted f32 inputs) offsets, padded to 4-float alignment ----
#define O_THW 0
#define O_PHW 4096
#define O_GGSW 8192
#define O_GXSW 315520
#define O_WS1W 319616
#define O_WS2W 329272
#define O_THCW 329324
#define O_PHCW 482988
#define O_GGCW 636652
#define O_GXCW 644844
#define O_WC1W 798508
#define O_WC2W 798772
#define O_THS 798780
#define O_THB 798812
#define O_PHS 798844
#define O_PHB 798876
#define O_GGSS 798908
#define O_GGSB 799104
#define O_GXSS 799300
#define O_GXSB 799332
#define O_WS1S 799364
#define O_WS1B 799416
#define O_WS2S 799468
#define O_WS2B 799472
#define O_THCS 799476
#define O_THCB 799672
#define O_PHCS 799868
#define O_PHCB 800064
#define O_GGCS 800260
#define O_GGCB 800292
#define O_GXCS 800324
#define O_GXCB 800520
#define O_WC1S 800716
#define O_WC1B 800724
#define O_WC2S 800732
#define O_WC2B 800736
#define WF_TOTAL 800768

static const int SRC_SIZES[36] = {
  4096,4096,307328,4096,9653,49,153664,153664,8192,153664,264,8,
  32,32,32,32,196,196,32,32,49,49,1,1,196,196,196,196,32,32,196,196,8,8,1,1};
static const int DST_OFF[36] = {
  O_THW,O_PHW,O_GGSW,O_GXSW,O_WS1W,O_WS2W,O_THCW,O_PHCW,O_GGCW,O_GXCW,O_WC1W,O_WC2W,
  O_THS,O_THB,O_PHS,O_PHB,O_GGSS,O_GGSB,O_GXSS,O_GXSB,O_WS1S,O_WS1B,O_WS2S,O_WS2B,
  O_THCS,O_THCB,O_PHCS,O_PHCB,O_GGCS,O_GGCB,O_GXCS,O_GXCB,O_WC1S,O_WC1B,O_WC2S,O_WC2B};

struct ConvArgs { const void* p[36]; int cum[37]; int dst[36]; };

typedef __attribute__((ext_vector_type(8))) short short8;   // 8 bf16 (4 VGPRs)
typedef __attribute__((ext_vector_type(4))) float fragf4;   // MFMA C/D

union FragU { unsigned int w[4]; short8 s8; };

__device__ __forceinline__ float sigf(float v){ return 1.0f/(1.0f+expf(-v)); }
__device__ __forceinline__ float hb2f(unsigned short h){ return __uint_as_float(((unsigned)h)<<16); }
__device__ __forceinline__ unsigned short f2hb(float v){
  __hip_bfloat16 hb = __float2bfloat16(v);
  return *reinterpret_cast<unsigned short*>(&hb);
}
__device__ __forceinline__ float loadx(const void* x, int flag, size_t idx){
  if (flag) return hb2f(((const unsigned short*)x)[idx]);
  return ((const float*)x)[idx];
}

// ---- kd: dtype probe. bf16 data -> ~all sane exponents; f32-misread -> ~62%.
__global__ void kd_detect(const void* x, int* flag){
  __shared__ int cnt[256];
  int t = threadIdx.x;
  const unsigned short* h = (const unsigned short*)x;
  int c = 0;
  for (int k=0;k<4;k++){
    unsigned short v = h[t*4+k];
    int e = (v>>7)&0xFF;
    c += (e==0 || (e>=97 && e<=157)) ? 1 : 0;
  }
  cnt[t] = c;
  __syncthreads();
  for (int s=128; s; s>>=1){ if (t<s) cnt[t]+=cnt[t+s]; __syncthreads(); }
  if (t==0) *flag = (cnt[0] >= 973) ? 1 : 0;
}

// ---- kc: convert all non-x inputs to f32 arena wf
__global__ void kc_convert(ConvArgs a, const int* flagp, float* wf){
  int flag = *flagp;
  int g = blockIdx.x*256 + threadIdx.x;
  if (g >= a.cum[36]) return;
  int i = 0;
  while (g >= a.cum[i+1]) i++;
  int local = g - a.cum[i];
  float v;
  if (flag) v = hb2f(((const unsigned short*)a.p[i])[local]);
  else      v = ((const float*)a.p[i])[local];
  wf[a.dst[i] + local] = v;
}

// ---- kw: bf16 copies of thc/phc/gxc weights for MFMA (lossless if input bf16)
__global__ void kw_wbf(const float* wf, unsigned short* wbf){
  int i = blockIdx.x*256 + threadIdx.x;
  if (i >= 3*IS*HW) return;
  int which = i/(IS*HW), r = i - which*(IS*HW);
  int off = which==0?O_THCW:(which==1?O_PHCW:O_GXCW);
  wbf[i] = f2hb(wf[off + r]);
}

// ---- k0: ws1bf [64][224] bf16 (zero-padded W1aug: col0 = gx weight)
__global__ void k0_ws1bf(const float* wf, unsigned int* ws1bf32){
  int i = blockIdx.x*256 + threadIdx.x;      // 64*112 u32
  if (i >= 64*112) return;
  int o2 = i/112, k2 = i - o2*112;
  int k = k2*2;
  float v0 = (o2<DS && k<197)   ? wf[O_WS1W + o2*197 + k]   : 0.f;
  float v1 = (o2<DS && k+1<197) ? wf[O_WS1W + o2*197 + k+1] : 0.f;
  ws1bf32[i] = (unsigned)f2hb(v0) | ((unsigned)f2hb(v1)<<16);
}

// ---- k1: theta/phi projections [b,32,784] f32
__global__ void k1_proj(const void* x, const int* flagp, const float* wf,
                        float* theta, float* phi){
  int flag = *flagp;
  int idx = blockIdx.x*256 + threadIdx.x;    // 64*64*784 exact
  int p = idx % HW; int o = (idx/HW)&63; int b = idx/(HW*64);
  int grp = o >> 5, r = o & 31;
  const float* w = wf + O_THW + grp*4096 + r*CC;
  float acc = 0.f;
  if (flag){
    const unsigned short* xb = (const unsigned short*)x + (size_t)b*CC*HW + p;
    #pragma unroll 8
    for (int c=0;c<CC;c+=4){
      float4 wv = *(const float4*)(w+c);
      acc += wv.x*hb2f(xb[(c+0)*HW]) + wv.y*hb2f(xb[(c+1)*HW])
           + wv.z*hb2f(xb[(c+2)*HW]) + wv.w*hb2f(xb[(c+3)*HW]);
    }
  } else {
    const float* xb = (const float*)x + (size_t)b*CC*HW + p;
    #pragma unroll 8
    for (int c=0;c<CC;c+=4){
      float4 wv = *(const float4*)(w+c);
      acc += wv.x*xb[(c+0)*HW] + wv.y*xb[(c+1)*HW]
           + wv.z*xb[(c+2)*HW] + wv.w*xb[(c+3)*HW];
    }
  }
  float sc = wf[O_THS + grp*64 + r], sh = wf[O_THB + grp*64 + r];
  float v = fmaxf(sc*acc + sh, 0.f);
  float* dst = grp ? phi : theta;
  dst[((size_t)b*IC + r)*HW + p] = v;
}

// ---- k2: g_xs[b,p] = mean_r relu(gxs_s[r]*dot(gxs_w[r,:],x[b,:,p])+gxs_b[r])
__global__ void k2_gxs(const void* x, const int* flagp, const float* wf, float* g_xs){
  int flag = *flagp;
  int idx = blockIdx.x*256 + threadIdx.x;    // 64*784 exact
  int p = idx % HW, b = idx / HW;
  float acc[32];
  #pragma unroll
  for (int r=0;r<32;r++) acc[r]=0.f;
  for (int c0=0;c0<CC;c0+=32){
    float xv[32];
    if (flag){
      const unsigned short* xb = (const unsigned short*)x + (size_t)b*CC*HW + p;
      #pragma unroll
      for (int cc=0;cc<32;cc++) xv[cc] = hb2f(xb[(c0+cc)*HW]);
    } else {
      const float* xb = (const float*)x + (size_t)b*CC*HW + p;
      #pragma unroll
      for (int cc=0;cc<32;cc++) xv[cc] = xb[(c0+cc)*HW];
    }
    #pragma unroll
    for (int r=0;r<32;r++){
      const float* wrow = wf + O_GXSW + r*CC + c0;
      #pragma unroll
      for (int cc=0;cc<32;cc+=4){
        float4 wv = *(const float4*)(wrow+cc);
        acc[r] += wv.x*xv[cc]+wv.y*xv[cc+1]+wv.z*xv[cc+2]+wv.w*xv[cc+3];
      }
    }
  }
  float m = 0.f;
  #pragma unroll
  for (int r=0;r<32;r++) m += fmaxf(wf[O_GXSS+r]*acc[r]+wf[O_GXSB+r], 0.f);
  g_xs[idx] = m*(1.f/32.f);
}

// ---- k3 v2: Aphi[b,o,c] = sum_j ggs_w[o,j]*phi[b,c,j] ; Atheta with w2/theta
__global__ __launch_bounds__(64) void k3_afact(const float* wf, const float* theta,
                                               const float* phi,
                                               float* Aphi, float* Atheta){
  __shared__ __align__(16) float Wl[32*60];
  __shared__ __align__(16) float Sl[32*60];
  int t = threadIdx.x;                     // 64 threads
  int ot = blockIdx.x % 7;
  int b  = (blockIdx.x/7) & 63;
  int which = blockIdx.x / (7*64);
  const float* src = which ? theta : phi;
  float* dst = which ? Atheta : Aphi;
  const float* wbase = wf + O_GGSW + (which ? HW : 0);
  int o0 = ot*32;
  int oq = t & 7, cq = t >> 3;
  float acc[4][4];
  #pragma unroll
  for (int oo=0;oo<4;oo++)
    #pragma unroll
    for (int cc=0;cc<4;cc++) acc[oo][cc]=0.f;

  for (int ch=0; ch<14; ch++){
    int j0 = ch*56;
    __syncthreads();
    #pragma unroll
    for (int pass=0; pass<7; pass++){
      int i = pass*64 + t;                 // 448 quads each for W and S
      int row = i/14, jq = i - row*14;
      int o = o0 + row;
      float4 wv = make_float4(0.f,0.f,0.f,0.f);
      if (o < IS) wv = *(const float4*)(wbase + (size_t)o*(2*HW) + j0 + 4*jq);
      *(float4*)(Wl + row*60 + 4*jq) = wv;
      *(float4*)(Sl + row*60 + 4*jq) =
          *(const float4*)(src + ((size_t)b*IC + row)*HW + j0 + 4*jq);
    }
    __syncthreads();
    #pragma unroll
    for (int jq=0; jq<14; jq++){
      float4 w4[4], s4[4];
      #pragma unroll
      for (int oo=0;oo<4;oo++) w4[oo] = *(const float4*)(Wl + (oq+8*oo)*60 + 4*jq);
      #pragma unroll
      for (int cc=0;cc<4;cc++) s4[cc] = *(const float4*)(Sl + (cq+8*cc)*60 + 4*jq);
      #pragma unroll
      for (int oo=0;oo<4;oo++)
        #pragma unroll
        for (int cc=0;cc<4;cc++)
          acc[oo][cc] += w4[oo].x*s4[cc].x + w4[oo].y*s4[cc].y
                       + w4[oo].z*s4[cc].z + w4[oo].w*s4[cc].w;
    }
  }
  #pragma unroll
  for (int oo=0;oo<4;oo++){
    int o = o0 + oq + 8*oo;
    if (o >= IS) continue;
    #pragma unroll
    for (int cc=0;cc<4;cc++){
      int c = cq + 8*cc;
      dst[((size_t)b*IS + o)*IC + c] = acc[oo][cc];
    }
  }
}

// ---- k4 v6 (MFMA): fused spatial chain per (b, 64-p tile).
#define ALS 33    // Al/Sl u32 stride
#define GTS 113   // Gt u32 stride (226 u16)
union K4Sh {
  struct { unsigned int Al[208*ALS]; unsigned int Sl[64*ALS]; } s1;
  unsigned int Gt[64*GTS];
};
__global__ __launch_bounds__(256,3) void k4_mfma(const void* x, const int* flagp,
    const float* wf, const float* theta, const float* phi,
    const float* Aphi, const float* Atheta, const float* g_xs,
    const unsigned int* ws1bf32, unsigned short* x1tp)
{
  __shared__ K4Sh sh;
  __shared__ float ash[64];
  int flag = *flagp;
  int t = threadIdx.x;
  int pt = blockIdx.x % 13, b = blockIdx.x / 13;
  int p0 = pt*64;
  int lane = t & 63, w = t >> 6;
  int col = lane & 15, kq = lane >> 4;

  const float* Ab = Aphi   + (size_t)b*IS*IC;
  const float* Tb = Atheta + (size_t)b*IS*IC;
  for (int i=t; i<208*32; i+=256){
    int o = i>>5, cp = i&31;
    unsigned int v = 0u;
    if (o < IS){
      const float* src = (cp<16 ? Ab : Tb) + o*IC + (cp&15)*2;
      v = (unsigned)f2hb(src[0]) | ((unsigned)f2hb(src[1])<<16);
    }
    sh.s1.Al[o*ALS + cp] = v;
  }
  for (int i=t; i<32*64; i+=256){
    int c2 = i>>6, pp = i&63;
    int p = p0+pp;
    unsigned int v = 0u;
    if (p < HW){
      int c = c2*2;
      const float* s0 = (c<32   ? theta : phi) + ((size_t)b*IC + (c&31))*HW + p;
      const float* s1 = (c+1<32 ? theta : phi) + ((size_t)b*IC + ((c+1)&31))*HW + p;
      v = (unsigned)f2hb(*s0) | ((unsigned)f2hb(*s1)<<16);
    }
    sh.s1.Sl[pp*ALS + c2] = v;
  }
  __syncthreads();

  fragf4 acc1[13];
  #pragma unroll
  for (int nt=0; nt<13; nt++)
    #pragma unroll
    for (int r=0;r<4;r++) acc1[nt][r] = 0.f;
  #pragma unroll
  for (int kk=0; kk<2; kk++){
    FragU af;
    #pragma unroll
    for (int q=0;q<4;q++) af.w[q] = sh.s1.Sl[(w*16+col)*ALS + kk*16 + kq*4 + q];
    #pragma unroll
    for (int nt=0; nt<13; nt++){
      FragU bf;
      #pragma unroll
      for (int q=0;q<4;q++) bf.w[q] = sh.s1.Al[(nt*16+col)*ALS + kk*16 + kq*4 + q];
      acc1[nt] = __builtin_amdgcn_mfma_f32_16x16x32_bf16(af.s8, bf.s8, acc1[nt], 0,0,0);
    }
  }
  __syncthreads();   // Al/Sl dead; Gt aliases them

  unsigned short* Gt16 = (unsigned short*)sh.Gt;
  for (int i=t; i<64*9; i+=256){
    int pp = i/9, q = i - pp*9;
    sh.Gt[pp*GTS + 104 + q] = 0u;
  }
  if (t < 64){
    int p = p0 + t;
    float gx = (p < HW) ? g_xs[b*HW + p] : 0.f;
    Gt16[t*226 + 0] = f2hb(gx);
  }
  #pragma unroll
  for (int nt=0; nt<13; nt++){
    int o = nt*16 + col;
    float sc = wf[O_GGSS + o], shf = wf[O_GGSB + o];
    #pragma unroll
    for (int r=0;r<4;r++){
      int pp = w*16 + kq*4 + r;
      float g = fmaxf(sc*acc1[nt][r] + shf, 0.f);
      Gt16[pp*226 + 1 + o] = f2hb(g);
    }
  }
  __syncthreads();

  fragf4 acc2[4];
  #pragma unroll
  for (int nt=0; nt<4; nt++)
    #pragma unroll
    for (int r=0;r<4;r++) acc2[nt][r] = 0.f;
  #pragma unroll
  for (int kk=0; kk<7; kk++){
    FragU af;
    #pragma unroll
    for (int q=0;q<4;q++) af.w[q] = sh.Gt[(w*16+col)*GTS + kk*16 + kq*4 + q];
    #pragma unroll
    for (int nt=0; nt<4; nt++){
      FragU bf;
      #pragma unroll
      for (int q=0;q<4;q++) bf.w[q] = ws1bf32[(nt*16+col)*112 + kk*16 + kq*4 + q];
      acc2[nt] = __builtin_amdgcn_mfma_f32_16x16x32_bf16(af.s8, bf.s8, acc2[nt], 0,0,0);
    }
  }

  float wys[4] = {0.f,0.f,0.f,0.f};
  #pragma unroll
  for (int nt=0; nt<4; nt++){
    int o2 = nt*16 + col;
    bool vd = (o2 < DS);
    float s1 = vd ? wf[O_WS1S+o2] : 0.f;
    float b1 = vd ? wf[O_WS1B+o2] : 0.f;
    float w2 = vd ? wf[O_WS2W+o2] : 0.f;
    #pragma unroll
    for (int r=0;r<4;r++){
      float z = fmaxf(s1*acc2[nt][r] + b1, 0.f);
      wys[r] += w2*z;
    }
  }
  #pragma unroll
  for (int m=1; m<16; m<<=1){
    #pragma unroll
    for (int r=0;r<4;r++) wys[r] += __shfl_xor(wys[r], m, 16);
  }
  if (col == 0){
    float s2 = wf[O_WS2S], b2 = wf[O_WS2B];
    #pragma unroll
    for (int r=0;r<4;r++){
      int pp = w*16 + kq*4 + r;
      ash[pp] = sigf(s2*wys[r] + b2);
    }
  }
  __syncthreads();

  for (int i=t; i<CC*64; i+=256){
    int c = i>>6, pp = i&63;
    int p = p0 + pp;
    if (p < HW){
      float v = ash[pp]*loadx(x, flag, (size_t)b*CC*HW + (size_t)c*HW + p);
      x1tp[(size_t)b*CC*HW + (size_t)c*HW + p] = f2hb(v);
    }
  }
}

// ---- k8 v2 (MFMA): out[b,s,c] = relu(sc*(sum_p W[s,p]*x1[b,p,c])+sh)
#define KST 40
__global__ __launch_bounds__(256,1) void k8_mfma(const unsigned short* wbf,
    const unsigned short* x1tp, const float* wf,
    float* thcp, float* phcp, float* gxcp)
{
  __shared__ __align__(16) unsigned short Al[208*KST];
  __shared__ __align__(16) unsigned short Bl[128*KST];
  int t = threadIdx.x;
  int b = blockIdx.x & 63;
  int which = blockIdx.x >> 6;
  const unsigned short* wsrc = wbf + (size_t)which*IS*HW;
  const unsigned short* xsrc = x1tp + (size_t)b*CC*HW;
  int lane = t & 63, w = t >> 6;
  int m16 = lane & 15, kq = lane >> 4;
  fragf4 acc[13][2];
  #pragma unroll
  for (int st=0; st<13; st++)
    #pragma unroll
    for (int ct=0; ct<2; ct++)
      #pragma unroll
      for (int r=0; r<4; r++) acc[st][ct][r] = 0.f;

  for (int kk=0; kk<25; kk++){
    int p0 = kk*32;
    __syncthreads();
    for (int i=t; i<208*4; i+=256){
      int row = i>>2, q = i&3;
      uint4 v = make_uint4(0u,0u,0u,0u);
      int p = p0 + q*8;
      if (row < IS && p+8 <= HW)
        v = *(const uint4*)(wsrc + (size_t)row*HW + p);
      *(uint4*)(Al + row*KST + q*8) = v;
    }
    for (int i=t; i<128*4; i+=256){
      int row = i>>2, q = i&3;
      uint4 v = make_uint4(0u,0u,0u,0u);
      int p = p0 + q*8;
      if (p+8 <= HW)
        v = *(const uint4*)(xsrc + (size_t)row*HW + p);
      *(uint4*)(Bl + row*KST + q*8) = v;
    }
    __syncthreads();
    short8 bfr[2];
    #pragma unroll
    for (int ct=0; ct<2; ct++){
      int n = (w*2+ct)*16 + m16;
      bfr[ct] = *(const short8*)(Bl + n*KST + kq*8);
    }
    #pragma unroll
    for (int st=0; st<13; st++){
      short8 af = *(const short8*)(Al + (st*16+m16)*KST + kq*8);
      acc[st][0] = __builtin_amdgcn_mfma_f32_16x16x32_bf16(af, bfr[0], acc[st][0], 0,0,0);
      acc[st][1] = __builtin_amdgcn_mfma_f32_16x16x32_bf16(af, bfr[1], acc[st][1], 0,0,0);
    }
  }
  const float* ss = wf + (which==0?O_THCS:(which==1?O_PHCS:O_GXCS));
  const float* sb = wf + (which==0?O_THCB:(which==1?O_PHCB:O_GXCB));
  float* dst = which==0?thcp:(which==1?phcp:gxcp);
  #pragma unroll
  for (int st=0; st<13; st++){
    #pragma unroll
    for (int r=0; r<4; r++){
      int s = st*16 + kq*4 + r;
      if (s >= IS) continue;
      float sc = ss[s], sh = sb[s];
      #pragma unroll
      for (int ct=0; ct<2; ct++){
        int c = (w*2+ct)*16 + m16;
        dst[((size_t)b*IS + s)*CC + c] = fmaxf(sc*acc[st][ct][r] + sh, 0.f);
      }
    }
  }
}

// ---- k9: Bph[b,s,o] = sum_j ggc_w[o,j]*phc[b,s,j]; Bth with w2/thc
__global__ void k9_bfact(const float* wf, const float* thcp, const float* phcp,
                         float* Bph, float* Bth)
{
  int gid = blockIdx.x*256 + threadIdx.x;    // 2*64*196*32 exact
  int o = gid & 31;
  int rest = gid >> 5;
  int s = rest % IS;
  int rb = rest / IS;           // [0,128)
  int b = rb & 63, which = rb >> 6;
  const float* src = which ? thcp : phcp;
  const float* wr = wf + O_GGCW + o*256 + which*CC;
  const float* sr = src + ((size_t)b*IS + s)*CC;
  float acc = 0.f;
  #pragma unroll 8
  for (int j=0;j<CC;j+=4){
    float4 wv = *(const float4*)(wr+j);
    float4 sv = *(const float4*)(sr+j);
    acc += wv.x*sv.x + wv.y*sv.y + wv.z*sv.z + wv.w*sv.w;
  }
  float* dst = which ? Bth : Bph;
  dst[((size_t)b*IS + s)*IC + o] = acc;
}

// ---- k10a: s-chunk partial accumulation. Grid (b x 14 chunks), thread (d, o-half).
// part[b][sc][32o][128d]; gxp[b][sc][128d] (o-half 0 only).
__global__ __launch_bounds__(256) void k10a_part(const float* thcp, const float* phcp,
    const float* gxcp, const float* Bph, const float* Bth,
    float* part, float* gxp)
{
  int t = threadIdx.x;
  int d = t & 127, oh = t >> 7;
  int sc = blockIdx.x % 14, b = blockIdx.x / 14;
  int s0 = sc*14;
  float acc[16];
  #pragma unroll
  for (int o=0;o<16;o++) acc[o]=0.f;
  float gxa = 0.f;
  for (int i=0;i<14;i++){
    int s = s0 + i;
    size_t base = ((size_t)b*IS + s)*CC + d;
    float tv = thcp[base], pv = phcp[base];
    if (oh == 0) gxa += gxcp[base];
    const float* bp = Bph + ((size_t)b*IS + s)*IC + oh*16;
    const float* bt = Bth + ((size_t)b*IS + s)*IC + oh*16;
    #pragma unroll
    for (int o=0;o<16;o++) acc[o] += bp[o]*tv + bt[o]*pv;
  }
  float* pb = part + (((size_t)b*14 + sc)*IC + oh*16)*CC + d;
  #pragma unroll
  for (int o=0;o<16;o++) pb[(size_t)o*CC] = acc[o];
  if (oh == 0) gxp[((size_t)b*14 + sc)*CC + d] = gxa;
}

// ---- k10b: reduce 14 chunks + wc1/wc2/sigmoid epilogue -> c_att[b,d]
__global__ void k10b_catt(const float* wf, const float* part, const float* gxp,
                          float* c_att)
{
  int idx = blockIdx.x*256 + threadIdx.x;    // 64*128 exact
  int d = idx & 127;
  int b = idx >> 7;
  float acc[IC];
  #pragma unroll
  for (int o=0;o<IC;o++) acc[o]=0.f;
  float gx = 0.f;
  for (int sc=0; sc<14; sc++){
    gx += gxp[((size_t)b*14 + sc)*CC + d];
    const float* pb = part + ((size_t)b*14 + sc)*IC*CC + d;
    #pragma unroll
    for (int o=0;o<IC;o++) acc[o] += pb[(size_t)o*CC];
  }
  gx *= (1.f/196.f);
  #pragma unroll
  for (int o=0;o<IC;o++) acc[o] = fmaxf(wf[O_GGCS+o]*acc[o]+wf[O_GGCB+o], 0.f);
  float acc2 = 0.f;
  #pragma unroll
  for (int o2=0;o2<8;o2++){
    float tt = wf[O_WC1W + o2*33]*gx;
    #pragma unroll
    for (int o=0;o<IC;o++) tt += wf[O_WC1W + o2*33+1+o]*acc[o];
    float z = fmaxf(wf[O_WC1S+o2]*tt + wf[O_WC1B+o2], 0.f);
    acc2 += wf[O_WC2W+o2]*z;
  }
  c_att[idx] = sigf(wf[O_WC2S]*acc2 + wf[O_WC2B]);
}

// ---- k12 v2: out[b,c,p] = c_att[b,c]*x1tp[b,c,p] — pure streaming
__global__ void k12_final(const int* flagp, const unsigned int* x1tp2,
                          const float* c_att, void* out)
{
  int i = blockIdx.x*256 + threadIdx.x;      // over BB*CC*HW/2 uints, exact
  int flag = *flagp;
  unsigned int v = x1tp2[i];
  float a = c_att[i/392];                    // 392 uints per (b,c) row
  float v0 = a*hb2f((unsigned short)(v & 0xffff));
  float v1 = a*hb2f((unsigned short)(v >> 16));
  if (flag){
    ((unsigned int*)out)[i] = (unsigned)f2hb(v0) | ((unsigned)f2hb(v1)<<16);
  } else {
    ((float*)out)[2*i+0] = v0;
    ((float*)out)[2*i+1] = v1;
  }
}

extern "C" void kernel_launch(void* const* d_in, const int* in_sizes, int n_in,
                              void* d_out, int out_size, void* d_ws, size_t ws_size,
                              hipStream_t stream)
{
  const void* x = d_in[0];

  float* W = (float*)d_ws;
  int*   flag  = (int*)W;                    // W[0..63] reserved
  float* wf    = W + 64;                     // 800768
  float* theta = wf + WF_TOTAL;              // 1605632
  float* phi   = theta + 1605632;            // 1605632
  float* g_xs  = phi + 1605632;              // 50176
  float* Aphi  = g_xs + 50176;               // 401408
  float* Atheta= Aphi + 401408;              // 401408
  unsigned short* x1tp = (unsigned short*)(Atheta + 401408); // 6422528 u16 = 3211264 f32 slots
  float* thcp  = Atheta + 401408 + 3211264;  // 1605632
  float* phcp  = thcp + 1605632;             // 1605632
  float* gxcp  = phcp + 1605632;             // 1605632
  float* Bph   = gxcp + 1605632;             // 401408
  float* Bth   = Bph + 401408;               // 401408
  unsigned int* ws1bf32 = (unsigned int*)(Bth + 401408);  // 7168 u32 (slot 9664)
  float* c_att = (float*)(ws1bf32) + 9664;   // 8192
  unsigned short* wbf = (unsigned short*)(c_att + 8192);  // 460992 u16 (~53.2 MiB total)
  // k10 partials reuse dead theta..Atheta region (4,064,256 contiguous floats):
  float* part = theta;                       // 64*14*32*128 = 3,670,016
  float* gxp  = theta + 3670016;             // 64*14*128  = 114,688 (fits: 3,784,704 < 4,064,256)

  ConvArgs ca;
  ca.cum[0] = 0;
  for (int i=0;i<36;i++){
    ca.p[i] = d_in[i+1];
    ca.cum[i+1] = ca.cum[i] + SRC_SIZES[i];
    ca.dst[i] = DST_OFF[i];
  }

  kd_detect<<<1, 256, 0, stream>>>(x, flag);
  kc_convert<<<(800716+255)/256, 256, 0, stream>>>(ca, flag, wf);
  kw_wbf<<<(3*IS*HW+255)/256, 256, 0, stream>>>(wf, wbf);
  k0_ws1bf<<<(64*112+255)/256, 256, 0, stream>>>(wf, ws1bf32);
  k1_proj<<<(BB*64*HW)/256, 256, 0, stream>>>(x, flag, wf, theta, phi);
  k2_gxs<<<(BB*HW)/256, 256, 0, stream>>>(x, flag, wf, g_xs);
  k3_afact<<<2*64*7, 64, 0, stream>>>(wf, theta, phi, Aphi, Atheta);
  k4_mfma<<<64*13, 256, 0, stream>>>(x, flag, wf, theta, phi, Aphi, Atheta,
      g_xs, ws1bf32, x1tp);
  k8_mfma<<<3*64, 256, 0, stream>>>(wbf, x1tp, wf, thcp, phcp, gxcp);
  k9_bfact<<<(2*BB*IS*IC)/256, 256, 0, stream>>>(wf, thcp, phcp, Bph, Bth);
  k10a_part<<<64*14, 256, 0, stream>>>(thcp, phcp, gxcp, Bph, Bth, part, gxp);
  k10b_catt<<<(BB*CC)/256, 256, 0, stream>>>(wf, part, gxp, c_att);
  k12_final<<<(BB*CC*HW/2)/256, 256, 0, stream>>>(flag, (const unsigned int*)x1tp,
      c_att, d_out);
}